// Round 18
// baseline (307.043 us; speedup 1.0000x reference)
//
#include <hip/hip_runtime.h>
#include <hip/hip_bf16.h>
#include <hip/hip_cooperative_groups.h>
#include <stdint.h>

typedef __attribute__((ext_vector_type(8))) short bf16x8;
typedef __attribute__((ext_vector_type(4))) float f32x4;

__device__ __forceinline__ unsigned short f2bf(float f) {
  __hip_bfloat16 h = __float2bfloat16(f);
  return *reinterpret_cast<unsigned short*>(&h);
}

// ---------------- cooperative prep+quant: absmax -> (x-cast || reduce) -> quantize ----------------
// Phase 1: each thread loads its w1/w2 chunk (5 uint4 each, statically indexed)
//   into registers, computes |.| max; block-reduce -> pmax[tensor][block].
// grid.sync()
// Phase 2: blocks 0/1 reduce 512 partials -> gbits[tensor]; ALL blocks x-cast.
// grid.sync()
// Phase 3: quantize from REGISTERS (no w re-read), store bf16.
// Deterministic: uint-max is order-independent; fixed work assignment.
__global__ __launch_bounds__(256)
void prepquant_coop(const float* __restrict__ w1, const float* __restrict__ w2,
                    const float* __restrict__ x, int n4w, int n4x,
                    const int* __restrict__ bits,
                    unsigned int* __restrict__ pmax,   // [2][512]
                    unsigned int* __restrict__ gbits,  // [2]
                    unsigned short* __restrict__ o1, unsigned short* __restrict__ o2,
                    unsigned short* __restrict__ ox) {
  cooperative_groups::grid_group grid = cooperative_groups::this_grid();
  const int tid = blockIdx.x * blockDim.x + threadIdx.x;  // 0..131071
  constexpr int NTHR = 512 * 256;

  // ---- phase 1: load w chunks to registers + absmax ----
  const uint4* w14 = reinterpret_cast<const uint4*>(w1);
  const uint4* w24 = reinterpret_cast<const uint4*>(w2);
  uint4 s1[5], s2[5];
  unsigned int m1 = 0u, m2 = 0u;
#pragma unroll
  for (int k = 0; k < 5; ++k) {
    const int i = tid + k * NTHR;
    if (k < 4 || i < n4w) {
      uint4 v = w14[i];
      s1[k] = v;
      m1 = max(m1, max(max(v.x & 0x7fffffffu, v.y & 0x7fffffffu),
                       max(v.z & 0x7fffffffu, v.w & 0x7fffffffu)));
      uint4 u = w24[i];
      s2[k] = u;
      m2 = max(m2, max(max(u.x & 0x7fffffffu, u.y & 0x7fffffffu),
                       max(u.z & 0x7fffffffu, u.w & 0x7fffffffu)));
    }
  }
  __shared__ unsigned int red[2][256];
  red[0][threadIdx.x] = m1;
  red[1][threadIdx.x] = m2;
  __syncthreads();
  for (int s = 128; s > 0; s >>= 1) {
    if ((int)threadIdx.x < s) {
      red[0][threadIdx.x] = max(red[0][threadIdx.x], red[0][threadIdx.x + s]);
      red[1][threadIdx.x] = max(red[1][threadIdx.x], red[1][threadIdx.x + s]);
    }
    __syncthreads();
  }
  if (threadIdx.x == 0) {
    pmax[blockIdx.x] = red[0][0];
    pmax[512 + blockIdx.x] = red[1][0];
  }
  __threadfence();
  grid.sync();

  // ---- phase 2: blocks 0/1 reduce partials; everyone x-casts ----
  if (blockIdx.x < 2) {
    const unsigned int* p = pmax + blockIdx.x * 512;
    unsigned int mm = max(p[threadIdx.x], p[threadIdx.x + 256]);
    red[0][threadIdx.x] = mm;
    __syncthreads();
    for (int s = 128; s > 0; s >>= 1) {
      if ((int)threadIdx.x < s)
        red[0][threadIdx.x] = max(red[0][threadIdx.x], red[0][threadIdx.x + s]);
      __syncthreads();
    }
    if (threadIdx.x == 0) gbits[blockIdx.x] = red[0][0];
    __threadfence();
  }
  {
    const float4* x4 = reinterpret_cast<const float4*>(x);
    ushort4* o4 = reinterpret_cast<ushort4*>(ox);
    for (int i = tid; i < n4x; i += NTHR) {
      float4 v = x4[i];
      o4[i] = make_ushort4(f2bf(v.x), f2bf(v.y), f2bf(v.z), f2bf(v.w));
    }
  }
  grid.sync();

  // ---- phase 3: quantize from registers ----
  const float qmax = (float)((1 << (*bits - 1)) - 1);
  const float sc1 = __uint_as_float(gbits[0]) / qmax;
  const float sc2 = __uint_as_float(gbits[1]) / qmax;
  ushort4* o14 = reinterpret_cast<ushort4*>(o1);
  ushort4* o24 = reinterpret_cast<ushort4*>(o2);
#pragma unroll
  for (int k = 0; k < 5; ++k) {
    const int i = tid + k * NTHR;
    if (k < 4 || i < n4w) {
      float4 v = *reinterpret_cast<float4*>(&s1[k]);
      o14[i] = make_ushort4(
          f2bf(fminf(fmaxf(rintf(v.x / sc1), -qmax), qmax) * sc1),
          f2bf(fminf(fmaxf(rintf(v.y / sc1), -qmax), qmax) * sc1),
          f2bf(fminf(fmaxf(rintf(v.z / sc1), -qmax), qmax) * sc1),
          f2bf(fminf(fmaxf(rintf(v.w / sc1), -qmax), qmax) * sc1));
      float4 u = *reinterpret_cast<float4*>(&s2[k]);
      o24[i] = make_ushort4(
          f2bf(fminf(fmaxf(rintf(u.x / sc2), -qmax), qmax) * sc2),
          f2bf(fminf(fmaxf(rintf(u.y / sc2), -qmax), qmax) * sc2),
          f2bf(fminf(fmaxf(rintf(u.z / sc2), -qmax), qmax) * sc2),
          f2bf(fminf(fmaxf(rintf(u.w / sc2), -qmax), qmax) * sc2));
    }
  }
}

// ---------------- GEMM1: 128x128, BK=32, dbuf + counted vmcnt(4) (r12/r13/r17 proven) ----------------
template<bool PRIO, bool RELU, bool BF16_OUT>
__global__ __launch_bounds__(256, 4)
void gemm_bt32(const unsigned short* __restrict__ A,  // [M,K] bf16 bits
               const unsigned short* __restrict__ B,  // [N,K] bf16 bits
               const float* __restrict__ bias,        // [N]
               void* __restrict__ Cout,               // [M,N] bf16 or f32
               int M, int N, int K, int gx) {
  constexpr int BK = 32, MF = 4;
  __shared__ __attribute__((aligned(16))) unsigned short As[2][128 * BK];
  __shared__ __attribute__((aligned(16))) unsigned short Bs[2][128 * BK];

  // bijective XCD swizzle (T1/m204)
  const int nwg = gridDim.x;
  const int orig = blockIdx.x;
  const int q = nwg >> 3, r = nwg & 7;
  const int xcd = orig & 7, cidx = orig >> 3;
  const int wgid = (xcd < r ? xcd * (q + 1) : r * (q + 1) + (xcd - r) * q) + cidx;
  const int bx = wgid % gx;
  const int by = wgid / gx;

  const int tid = threadIdx.x;
  const int lane = tid & 63;
  const int wave = tid >> 6;
  const int wr = wave >> 1;
  const int wc = wave & 1;
  const long brow = (long)by * 128;
  const long bcol = (long)bx * 128;

  f32x4 acc[MF][4] = {};

  const int srow = lane >> 2;
  const int gslot = ((lane & 3) ^ ((lane >> 3) & 3)) * 8;
  const int fr = lane & 15;
  const int fs = lane >> 4;

  auto stage = [&](int k0, int b) {
#pragma unroll
    for (int it = 0; it < 2; ++it) {
      const int c = it * 4 + wave;
      const unsigned short* ga = A + (brow + c * 16 + srow) * (long)K + k0 + gslot;
      __builtin_amdgcn_global_load_lds(
          (const __attribute__((address_space(1))) void*)ga,
          (__attribute__((address_space(3))) void*)(&As[b][c * 512]), 16, 0, 0);
    }
#pragma unroll
    for (int it = 0; it < 2; ++it) {
      const int c = it * 4 + wave;
      const unsigned short* gb = B + (bcol + c * 16 + srow) * (long)K + k0 + gslot;
      __builtin_amdgcn_global_load_lds(
          (const __attribute__((address_space(1))) void*)gb,
          (__attribute__((address_space(3))) void*)(&Bs[b][c * 512]), 16, 0, 0);
    }
  };

  const int nt = K / BK;
  stage(0, 0);
  stage(BK, 1);

  for (int t = 0; t < nt; ++t) {
    const int b = t & 1;
    if (t < nt - 1) asm volatile("s_waitcnt vmcnt(4)" ::: "memory");
    else            asm volatile("s_waitcnt vmcnt(0)" ::: "memory");
    __builtin_amdgcn_s_barrier();

    const unsigned short* as = &As[b][0];
    const unsigned short* bs = &Bs[b][0];
    bf16x8 a[MF], bb[4];
#pragma unroll
    for (int m = 0; m < MF; ++m) {
      const int row = wr * 64 + m * 16 + fr;
      a[m] = *reinterpret_cast<const bf16x8*>(as + row * BK + ((fs ^ ((row >> 1) & 3)) * 8));
    }
#pragma unroll
    for (int n = 0; n < 4; ++n) {
      const int row = wc * 64 + n * 16 + fr;
      bb[n] = *reinterpret_cast<const bf16x8*>(bs + row * BK + ((fs ^ ((row >> 1) & 3)) * 8));
    }
    if (PRIO) __builtin_amdgcn_s_setprio(1);
#pragma unroll
    for (int m = 0; m < MF; ++m)
#pragma unroll
      for (int n = 0; n < 4; ++n)
        acc[m][n] = __builtin_amdgcn_mfma_f32_16x16x32_bf16(a[m], bb[n], acc[m][n], 0, 0, 0);
    if (PRIO) __builtin_amdgcn_s_setprio(0);

    asm volatile("s_waitcnt lgkmcnt(0)" ::: "memory");
    __builtin_amdgcn_sched_barrier(0);
    __builtin_amdgcn_s_barrier();
    if (t + 2 < nt) stage((t + 2) * BK, b);
  }

  const int fq = lane >> 4;
#pragma unroll
  for (int n = 0; n < 4; ++n) {
    const long col = bcol + wc * 64 + n * 16 + fr;
    const float bv = bias[col];
#pragma unroll
    for (int m = 0; m < MF; ++m) {
#pragma unroll
      for (int rr = 0; rr < 4; ++rr) {
        const long row = brow + wr * 64 + m * 16 + fq * 4 + rr;
        float v = acc[m][n][rr] + bv;
        if (RELU) v = fmaxf(v, 0.0f);
        if (BF16_OUT)
          ((unsigned short*)Cout)[row * N + col] = f2bf(v);
        else
          ((float*)Cout)[row * N + col] = v;
      }
    }
  }
}

// ---------------- GEMM2: round-11/13/17 kernel frozen (BM=64, BK=64, 3 blk/CU, setprio) ----------------
template<int BM, bool PRIO, bool RELU, bool BF16_OUT>
__global__ __launch_bounds__(256)
void gemm_bt(const unsigned short* __restrict__ A, const unsigned short* __restrict__ B,
             const float* __restrict__ bias, void* __restrict__ Cout,
             int M, int N, int K, int gx) {
  constexpr int BK = 64;
  constexpr int MF = BM / 32;
  __shared__ __attribute__((aligned(16))) unsigned short As[2][BM * BK];
  __shared__ __attribute__((aligned(16))) unsigned short Bs[2][128 * BK];

  const int nwg = gridDim.x;
  const int orig = blockIdx.x;
  const int q = nwg >> 3, r = nwg & 7;
  const int xcd = orig & 7, cidx = orig >> 3;
  const int wgid = (xcd < r ? xcd * (q + 1) : r * (q + 1) + (xcd - r) * q) + cidx;
  const int bx = wgid % gx;
  const int by = wgid / gx;

  const int tid = threadIdx.x;
  const int lane = tid & 63;
  const int wave = tid >> 6;
  const int wr = wave >> 1;
  const int wc = wave & 1;
  const long brow = (long)by * BM;
  const long bcol = (long)bx * 128;

  f32x4 acc[MF][4] = {};

  const int srow = lane >> 3;
  const int gslot = ((lane & 7) ^ (lane >> 3)) * 8;
  const int fr = lane & 15;
  const int fs = lane >> 4;

  auto stage = [&](int k0, int b) {
#pragma unroll
    for (int it = 0; it < BM / 32; ++it) {
      const int c = it * 4 + wave;
      const unsigned short* ga = A + (brow + c * 8 + srow) * (long)K + k0 + gslot;
      __builtin_amdgcn_global_load_lds(
          (const __attribute__((address_space(1))) void*)ga,
          (__attribute__((address_space(3))) void*)(&As[b][c * 512]), 16, 0, 0);
    }
#pragma unroll
    for (int it = 0; it < 4; ++it) {
      const int c = it * 4 + wave;
      const unsigned short* gb = B + (bcol + c * 8 + srow) * (long)K + k0 + gslot;
      __builtin_amdgcn_global_load_lds(
          (const __attribute__((address_space(1))) void*)gb,
          (__attribute__((address_space(3))) void*)(&Bs[b][c * 512]), 16, 0, 0);
    }
  };

  const int nt = K / BK;
  stage(0, 0);
  stage(BK, 1);

  for (int t = 0; t < nt; ++t) {
    const int b = t & 1;
    if (t < nt - 1) {
      if constexpr (BM == 128) asm volatile("s_waitcnt vmcnt(8)" ::: "memory");
      else                     asm volatile("s_waitcnt vmcnt(6)" ::: "memory");
    } else {
      asm volatile("s_waitcnt vmcnt(0)" ::: "memory");
    }
    __builtin_amdgcn_s_barrier();

    const unsigned short* as = &As[b][0];
    const unsigned short* bs = &Bs[b][0];
#pragma unroll
    for (int kk = 0; kk < 2; ++kk) {
      const int s = kk * 4 + fs;
      bf16x8 a[MF], bb[4];
#pragma unroll
      for (int m = 0; m < MF; ++m) {
        const int row = wr * (MF * 16) + m * 16 + fr;
        a[m] = *reinterpret_cast<const bf16x8*>(as + row * BK + ((s ^ (row & 7)) * 8));
      }
#pragma unroll
      for (int n = 0; n < 4; ++n) {
        const int row = wc * 64 + n * 16 + fr;
        bb[n] = *reinterpret_cast<const bf16x8*>(bs + row * BK + ((s ^ (row & 7)) * 8));
      }
      if (PRIO) __builtin_amdgcn_s_setprio(1);
#pragma unroll
      for (int m = 0; m < MF; ++m)
#pragma unroll
        for (int n = 0; n < 4; ++n)
          acc[m][n] = __builtin_amdgcn_mfma_f32_16x16x32_bf16(a[m], bb[n], acc[m][n], 0, 0, 0);
      if (PRIO) __builtin_amdgcn_s_setprio(0);
    }

    asm volatile("s_waitcnt lgkmcnt(0)" ::: "memory");
    __builtin_amdgcn_sched_barrier(0);
    __builtin_amdgcn_s_barrier();
    if (t + 2 < nt) stage((t + 2) * BK, b);
  }

  const int fq = lane >> 4;
#pragma unroll
  for (int n = 0; n < 4; ++n) {
    const long col = bcol + wc * 64 + n * 16 + fr;
    const float bv = bias[col];
#pragma unroll
    for (int m = 0; m < MF; ++m) {
#pragma unroll
      for (int rr = 0; rr < 4; ++rr) {
        const long row = brow + wr * (MF * 16) + m * 16 + fq * 4 + rr;
        float v = acc[m][n][rr] + bv;
        if (RELU) v = fmaxf(v, 0.0f);
        if (BF16_OUT)
          ((unsigned short*)Cout)[row * N + col] = f2bf(v);
        else
          ((float*)Cout)[row * N + col] = v;
      }
    }
  }
}

extern "C" void kernel_launch(void* const* d_in, const int* in_sizes, int n_in,
                              void* d_out, int out_size, void* d_ws, size_t ws_size,
                              hipStream_t stream) {
  const float* x  = (const float*)d_in[0];
  const float* w1 = (const float*)d_in[1];
  const float* b1 = (const float*)d_in[2];
  const float* w2 = (const float*)d_in[3];
  const float* b2 = (const float*)d_in[4];
  const int* bits = (const int*)d_in[5];

  const int M = 64 * 196;  // 12544 tokens
  const int D = 768, H = 3072;
  const int nx = M * D;
  const int nw1 = H * D;

  char* ws = (char*)d_ws;
  unsigned int* pmax  = (unsigned int*)ws;               // [2][512]
  unsigned int* gbits = (unsigned int*)(ws + 8192);      // [2]
  unsigned short* xb  = (unsigned short*)(ws + 16384);
  unsigned short* w1q = (unsigned short*)(ws + 16384 + (size_t)nx * 2);
  unsigned short* w2q = (unsigned short*)(ws + 16384 + (size_t)nx * 2 + (size_t)nw1 * 2);
  unsigned short* hb  = (unsigned short*)(ws + 16384 + (size_t)nx * 2 + (size_t)nw1 * 4);

  // cooperative prep+quant: 512 blocks x 256 thr (co-resident: 2 blk/CU)
  int n4w = nw1 / 4, n4x = nx / 4;
  void* args[] = {(void*)&w1, (void*)&w2, (void*)&x, (void*)&n4w, (void*)&n4x,
                  (void*)&bits, (void*)&pmax, (void*)&gbits,
                  (void*)&w1q, (void*)&w2q, (void*)&xb};
  hipLaunchCooperativeKernel((const void*)prepquant_coop, dim3(512), dim3(256),
                             args, 0, stream);

  // GEMM1: h = relu(x @ w1^T + b1), [12544,3072] bf16 ; 24x98 = 2352 blocks
  gemm_bt32<true, true, true><<<(H / 128) * (M / 128), 256, 0, stream>>>(
      xb, w1q, b1, hb, M, H, D, H / 128);
  // GEMM2: out = h @ w2^T + b2, [12544,768] f32 ; 6x196 = 1176 blocks
  gemm_bt<64, true, false, false><<<(D / 128) * (M / 64), 256, 0, stream>>>(
      hb, w2q, b2, d_out, M, D, H, D / 128);
}

// Round 19
// 184.387 us; speedup vs baseline: 1.6652x; 1.6652x over previous
//
#include <hip/hip_runtime.h>
#include <hip/hip_bf16.h>
#include <stdint.h>

typedef __attribute__((ext_vector_type(8))) short bf16x8;
typedef __attribute__((ext_vector_type(4))) float f32x4;

__device__ __forceinline__ unsigned short f2bf(float f) {
  __hip_bfloat16 h = __float2bfloat16(f);
  return *reinterpret_cast<unsigned short*>(&h);
}

// ---------------- prep: per-block absmax partials (y=0/1) + x->bf16 cast (y=2) ----------------
__global__ void prep_kernel(const float* __restrict__ w1, const float* __restrict__ w2,
                            const float* __restrict__ x, int n4w, int n4x,
                            unsigned int* __restrict__ pmax,
                            unsigned short* __restrict__ ox) {
  if (blockIdx.y == 2) {
    const float4* x4 = reinterpret_cast<const float4*>(x);
    ushort4* o4 = reinterpret_cast<ushort4*>(ox);
    for (int i = blockIdx.x * blockDim.x + threadIdx.x; i < n4x;
         i += gridDim.x * blockDim.x) {
      float4 v = x4[i];
      o4[i] = make_ushort4(f2bf(v.x), f2bf(v.y), f2bf(v.z), f2bf(v.w));
    }
    return;
  }
  const float* w = blockIdx.y ? w2 : w1;
  __shared__ unsigned int red[256];
  unsigned int m = 0u;
  const uint4* w4 = reinterpret_cast<const uint4*>(w);
  for (int i = blockIdx.x * blockDim.x + threadIdx.x; i < n4w;
       i += gridDim.x * blockDim.x) {
    uint4 v = w4[i];
    m = max(m, v.x & 0x7fffffffu);
    m = max(m, v.y & 0x7fffffffu);
    m = max(m, v.z & 0x7fffffffu);
    m = max(m, v.w & 0x7fffffffu);
  }
  red[threadIdx.x] = m;
  __syncthreads();
  for (int s = 128; s > 0; s >>= 1) {
    if ((int)threadIdx.x < s)
      red[threadIdx.x] = max(red[threadIdx.x], red[threadIdx.x + s]);
    __syncthreads();
  }
  if (threadIdx.x == 0) pmax[blockIdx.y * 512 + blockIdx.x] = red[0];
}

// ---------------- fake-quant w1/w2: reduce 512 partials, then quantize ----------------
__global__ void quant2_kernel(const float* __restrict__ w1, const float* __restrict__ w2,
                              int n4, const unsigned int* __restrict__ pmax,
                              const int* __restrict__ bits,
                              unsigned short* __restrict__ o1, unsigned short* __restrict__ o2) {
  __shared__ unsigned int red[256];
  const unsigned int* p = pmax + blockIdx.y * 512;
  red[threadIdx.x] = max(p[threadIdx.x], p[threadIdx.x + 256]);
  __syncthreads();
  for (int s = 128; s > 0; s >>= 1) {
    if ((int)threadIdx.x < s)
      red[threadIdx.x] = max(red[threadIdx.x], red[threadIdx.x + s]);
    __syncthreads();
  }
  const float qmax = (float)((1 << (*bits - 1)) - 1);
  const float scale = __uint_as_float(red[0]) / qmax;

  const float* w = blockIdx.y ? w2 : w1;
  unsigned short* o = blockIdx.y ? o2 : o1;
  const float4* w4 = reinterpret_cast<const float4*>(w);
  ushort4* o4 = reinterpret_cast<ushort4*>(o);
  for (int i = blockIdx.x * blockDim.x + threadIdx.x; i < n4;
       i += gridDim.x * blockDim.x) {
    float4 v = w4[i];
    float a = fminf(fmaxf(rintf(v.x / scale), -qmax), qmax) * scale;
    float b = fminf(fmaxf(rintf(v.y / scale), -qmax), qmax) * scale;
    float c = fminf(fmaxf(rintf(v.z / scale), -qmax), qmax) * scale;
    float d = fminf(fmaxf(rintf(v.w / scale), -qmax), qmax) * scale;
    o4[i] = make_ushort4(f2bf(a), f2bf(b), f2bf(c), f2bf(d));
  }
}

// ---------------- GEMM1: 128x128, BK=32, dbuf + counted vmcnt(4) (r12/r13/r17 proven) ----------------
// Swizzle (rounds 5/6/12/13/17 verified, 0 conflicts): chunk = 16 rows x 32
// elems; global source slot (lane&3)^((lane>>3)&3); ds_read slot fs^((row>>1)&3).
template<bool PRIO, bool RELU, bool BF16_OUT>
__global__ __launch_bounds__(256, 4)
void gemm_bt32(const unsigned short* __restrict__ A,  // [M,K] bf16 bits
               const unsigned short* __restrict__ B,  // [N,K] bf16 bits
               const float* __restrict__ bias,        // [N]
               void* __restrict__ Cout,               // [M,N] bf16 or f32
               int M, int N, int K, int gx) {
  constexpr int BK = 32, MF = 4;
  __shared__ __attribute__((aligned(16))) unsigned short As[2][128 * BK];
  __shared__ __attribute__((aligned(16))) unsigned short Bs[2][128 * BK];

  // bijective XCD swizzle (T1/m204)
  const int nwg = gridDim.x;
  const int orig = blockIdx.x;
  const int q = nwg >> 3, r = nwg & 7;
  const int xcd = orig & 7, cidx = orig >> 3;
  const int wgid = (xcd < r ? xcd * (q + 1) : r * (q + 1) + (xcd - r) * q) + cidx;
  const int bx = wgid % gx;
  const int by = wgid / gx;

  const int tid = threadIdx.x;
  const int lane = tid & 63;
  const int wave = tid >> 6;
  const int wr = wave >> 1;
  const int wc = wave & 1;
  const long brow = (long)by * 128;
  const long bcol = (long)bx * 128;

  f32x4 acc[MF][4] = {};

  const int srow = lane >> 2;
  const int gslot = ((lane & 3) ^ ((lane >> 3) & 3)) * 8;
  const int fr = lane & 15;
  const int fs = lane >> 4;

  auto stage = [&](int k0, int b) {
#pragma unroll
    for (int it = 0; it < 2; ++it) {
      const int c = it * 4 + wave;
      const unsigned short* ga = A + (brow + c * 16 + srow) * (long)K + k0 + gslot;
      __builtin_amdgcn_global_load_lds(
          (const __attribute__((address_space(1))) void*)ga,
          (__attribute__((address_space(3))) void*)(&As[b][c * 512]), 16, 0, 0);
    }
#pragma unroll
    for (int it = 0; it < 2; ++it) {
      const int c = it * 4 + wave;
      const unsigned short* gb = B + (bcol + c * 16 + srow) * (long)K + k0 + gslot;
      __builtin_amdgcn_global_load_lds(
          (const __attribute__((address_space(1))) void*)gb,
          (__attribute__((address_space(3))) void*)(&Bs[b][c * 512]), 16, 0, 0);
    }
  };

  const int nt = K / BK;
  stage(0, 0);
  stage(BK, 1);

  for (int t = 0; t < nt; ++t) {
    const int b = t & 1;
    if (t < nt - 1) asm volatile("s_waitcnt vmcnt(4)" ::: "memory");
    else            asm volatile("s_waitcnt vmcnt(0)" ::: "memory");
    __builtin_amdgcn_s_barrier();

    const unsigned short* as = &As[b][0];
    const unsigned short* bs = &Bs[b][0];
    bf16x8 a[MF], bb[4];
#pragma unroll
    for (int m = 0; m < MF; ++m) {
      const int row = wr * 64 + m * 16 + fr;
      a[m] = *reinterpret_cast<const bf16x8*>(as + row * BK + ((fs ^ ((row >> 1) & 3)) * 8));
    }
#pragma unroll
    for (int n = 0; n < 4; ++n) {
      const int row = wc * 64 + n * 16 + fr;
      bb[n] = *reinterpret_cast<const bf16x8*>(bs + row * BK + ((fs ^ ((row >> 1) & 3)) * 8));
    }
    if (PRIO) __builtin_amdgcn_s_setprio(1);
#pragma unroll
    for (int m = 0; m < MF; ++m)
#pragma unroll
      for (int n = 0; n < 4; ++n)
        acc[m][n] = __builtin_amdgcn_mfma_f32_16x16x32_bf16(a[m], bb[n], acc[m][n], 0, 0, 0);
    if (PRIO) __builtin_amdgcn_s_setprio(0);

    asm volatile("s_waitcnt lgkmcnt(0)" ::: "memory");
    __builtin_amdgcn_sched_barrier(0);
    __builtin_amdgcn_s_barrier();
    if (t + 2 < nt) stage((t + 2) * BK, b);
  }

  // epilogue: C/D layout col=lane&15, row=(lane>>4)*4+rr  [m89/m91 verified]
  const int fq = lane >> 4;
#pragma unroll
  for (int n = 0; n < 4; ++n) {
    const long col = bcol + wc * 64 + n * 16 + fr;
    const float bv = bias[col];
#pragma unroll
    for (int m = 0; m < MF; ++m) {
#pragma unroll
      for (int rr = 0; rr < 4; ++rr) {
        const long row = brow + wr * 64 + m * 16 + fq * 4 + rr;
        float v = acc[m][n][rr] + bv;
        if (RELU) v = fmaxf(v, 0.0f);
        if (BF16_OUT)
          ((unsigned short*)Cout)[row * N + col] = f2bf(v);
        else
          ((float*)Cout)[row * N + col] = v;
      }
    }
  }
}

// ---------------- GEMM2: round-11/13/17 kernel frozen (BM=64, BK=64, 3 blk/CU, setprio) ----------------
template<int BM, bool PRIO, bool RELU, bool BF16_OUT>
__global__ __launch_bounds__(256)
void gemm_bt(const unsigned short* __restrict__ A, const unsigned short* __restrict__ B,
             const float* __restrict__ bias, void* __restrict__ Cout,
             int M, int N, int K, int gx) {
  constexpr int BK = 64;
  constexpr int MF = BM / 32;
  __shared__ __attribute__((aligned(16))) unsigned short As[2][BM * BK];
  __shared__ __attribute__((aligned(16))) unsigned short Bs[2][128 * BK];

  const int nwg = gridDim.x;
  const int orig = blockIdx.x;
  const int q = nwg >> 3, r = nwg & 7;
  const int xcd = orig & 7, cidx = orig >> 3;
  const int wgid = (xcd < r ? xcd * (q + 1) : r * (q + 1) + (xcd - r) * q) + cidx;
  const int bx = wgid % gx;
  const int by = wgid / gx;

  const int tid = threadIdx.x;
  const int lane = tid & 63;
  const int wave = tid >> 6;
  const int wr = wave >> 1;
  const int wc = wave & 1;
  const long brow = (long)by * BM;
  const long bcol = (long)bx * 128;

  f32x4 acc[MF][4] = {};

  const int srow = lane >> 3;
  const int gslot = ((lane & 7) ^ (lane >> 3)) * 8;
  const int fr = lane & 15;
  const int fs = lane >> 4;

  auto stage = [&](int k0, int b) {
#pragma unroll
    for (int it = 0; it < BM / 32; ++it) {
      const int c = it * 4 + wave;
      const unsigned short* ga = A + (brow + c * 8 + srow) * (long)K + k0 + gslot;
      __builtin_amdgcn_global_load_lds(
          (const __attribute__((address_space(1))) void*)ga,
          (__attribute__((address_space(3))) void*)(&As[b][c * 512]), 16, 0, 0);
    }
#pragma unroll
    for (int it = 0; it < 4; ++it) {
      const int c = it * 4 + wave;
      const unsigned short* gb = B + (bcol + c * 8 + srow) * (long)K + k0 + gslot;
      __builtin_amdgcn_global_load_lds(
          (const __attribute__((address_space(1))) void*)gb,
          (__attribute__((address_space(3))) void*)(&Bs[b][c * 512]), 16, 0, 0);
    }
  };

  const int nt = K / BK;
  stage(0, 0);
  stage(BK, 1);

  for (int t = 0; t < nt; ++t) {
    const int b = t & 1;
    if (t < nt - 1) {
      if constexpr (BM == 128) asm volatile("s_waitcnt vmcnt(8)" ::: "memory");
      else                     asm volatile("s_waitcnt vmcnt(6)" ::: "memory");
    } else {
      asm volatile("s_waitcnt vmcnt(0)" ::: "memory");
    }
    __builtin_amdgcn_s_barrier();

    const unsigned short* as = &As[b][0];
    const unsigned short* bs = &Bs[b][0];
#pragma unroll
    for (int kk = 0; kk < 2; ++kk) {
      const int s = kk * 4 + fs;
      bf16x8 a[MF], bb[4];
#pragma unroll
      for (int m = 0; m < MF; ++m) {
        const int row = wr * (MF * 16) + m * 16 + fr;
        a[m] = *reinterpret_cast<const bf16x8*>(as + row * BK + ((s ^ (row & 7)) * 8));
      }
#pragma unroll
      for (int n = 0; n < 4; ++n) {
        const int row = wc * 64 + n * 16 + fr;
        bb[n] = *reinterpret_cast<const bf16x8*>(bs + row * BK + ((s ^ (row & 7)) * 8));
      }
      if (PRIO) __builtin_amdgcn_s_setprio(1);
#pragma unroll
      for (int m = 0; m < MF; ++m)
#pragma unroll
        for (int n = 0; n < 4; ++n)
          acc[m][n] = __builtin_amdgcn_mfma_f32_16x16x32_bf16(a[m], bb[n], acc[m][n], 0, 0, 0);
      if (PRIO) __builtin_amdgcn_s_setprio(0);
    }

    asm volatile("s_waitcnt lgkmcnt(0)" ::: "memory");
    __builtin_amdgcn_sched_barrier(0);
    __builtin_amdgcn_s_barrier();
    if (t + 2 < nt) stage((t + 2) * BK, b);
  }

  const int fq = lane >> 4;
#pragma unroll
  for (int n = 0; n < 4; ++n) {
    const long col = bcol + wc * 64 + n * 16 + fr;
    const float bv = bias[col];
#pragma unroll
    for (int m = 0; m < MF; ++m) {
#pragma unroll
      for (int rr = 0; rr < 4; ++rr) {
        const long row = brow + wr * (MF * 16) + m * 16 + fq * 4 + rr;
        float v = acc[m][n][rr] + bv;
        if (RELU) v = fmaxf(v, 0.0f);
        if (BF16_OUT)
          ((unsigned short*)Cout)[row * N + col] = f2bf(v);
        else
          ((float*)Cout)[row * N + col] = v;
      }
    }
  }
}

extern "C" void kernel_launch(void* const* d_in, const int* in_sizes, int n_in,
                              void* d_out, int out_size, void* d_ws, size_t ws_size,
                              hipStream_t stream) {
  const float* x  = (const float*)d_in[0];
  const float* w1 = (const float*)d_in[1];
  const float* b1 = (const float*)d_in[2];
  const float* w2 = (const float*)d_in[3];
  const float* b2 = (const float*)d_in[4];
  const int* bits = (const int*)d_in[5];

  const int M = 64 * 196;  // 12544 tokens
  const int D = 768, H = 3072;
  const int nx = M * D;
  const int nw1 = H * D;

  char* ws = (char*)d_ws;
  unsigned short* xb  = (unsigned short*)(ws + 256);
  unsigned short* w1q = (unsigned short*)(ws + 256 + (size_t)nx * 2);
  unsigned short* w2q = (unsigned short*)(ws + 256 + (size_t)nx * 2 + (size_t)nw1 * 2);
  unsigned short* hb  = (unsigned short*)(ws + 256 + (size_t)nx * 2 + (size_t)nw1 * 4);
  // pmax[2][512] aliased over hb's head: dead by the time GEMM1 writes hb
  // (prep -> quant2 -> GEMM1 are stream-serial; rewritten every call).
  unsigned int* pmax = (unsigned int*)hb;

  prep_kernel<<<dim3(512, 3), 256, 0, stream>>>(w1, w2, x, nw1 / 4, nx / 4, pmax, xb);
  quant2_kernel<<<dim3(512, 2), 256, 0, stream>>>(w1, w2, nw1 / 4, pmax, bits, w1q, w2q);

  // GEMM1: h = relu(x @ w1^T + b1), [12544,3072] bf16 ; 24x98 = 2352 blocks,
  // nt=24, 32KB LDS (r13/r17 config)
  gemm_bt32<true, true, true><<<(H / 128) * (M / 128), 256, 0, stream>>>(
      xb, w1q, b1, hb, M, H, D, H / 128);
  // GEMM2: out = h @ w2^T + b2, [12544,768] f32 ; 6x196 = 1176 blocks, nt=48,
  // 48KB LDS -> 3 blk/CU (round-11/13/17 frozen)
  gemm_bt<64, true, false, false><<<(D / 128) * (M / 64), 256, 0, stream>>>(
      hb, w2q, b2, d_out, M, D, H, D / 128);
}